// Round 7
// baseline (141.565 us; speedup 1.0000x reference)
//
#include <hip/hip_runtime.h>
#include <hip/hip_bf16.h>

// B=16, K=32, H=W=28, HID=OUT=64, NOPS=8
// ws layout: h2b bf16[512*3136] | feat f32[512*64] | s[16*64] | t7c[16*64] | x8[16*64]
//            | cnt i32[16] | Wt f32[8*64*64] ([m][e][d]) | fcwb bf16[64*3136]
//            | part f32[14*512*64]

typedef __attribute__((ext_vector_type(8))) short short8;
typedef __attribute__((ext_vector_type(4))) float f32x4;

__device__ __forceinline__ f32x4 mfma_bf16(short8 a, short8 b, f32x4 c) {
  return __builtin_amdgcn_mfma_f32_16x16x32_bf16(a, b, c, 0, 0, 0);
}

// float -> bf16 bits, round-to-nearest-even (finite inputs only)
__device__ __forceinline__ unsigned short f2bs(float f) {
  unsigned int u = __float_as_uint(f);
  unsigned int r = u + 0x7fffu + ((u >> 16) & 1u);
  return (unsigned short)(r >> 16);
}
// packed 2xfp32 -> 2xbf16 (v_cvt_pk_bf16_f32 on gfx950)
__device__ __forceinline__ unsigned int pk2(float x, float y) {
  union { __hip_bfloat162 h; unsigned int u; } cv;
  cv.h = __float22bfloat162_rn(make_float2(x, y));
  return cv.u;
}
__device__ __forceinline__ void stb4(short* p, float4 v) {
  *(unsigned int*)(p)     = pk2(v.x, v.y);
  *(unsigned int*)(p + 2) = pk2(v.z, v.w);
}

// ---------------- k12: fused conv1+pool -> LDS -> conv2(MFMA)+pool -> h2b ----------------
// blocks >= 512 do weight prep (Wt transpose, fcwb cast)
__global__ __launch_bounds__(256, 2) void k12_conv(const float* __restrict__ x,
    const float* __restrict__ w1, const float* __restrict__ b1,
    const float* __restrict__ w2, const float* __restrict__ b2,
    short* __restrict__ h2b,
    const float* __restrict__ eqw, float* __restrict__ Wt,
    const float* __restrict__ fcw, short* __restrict__ fcwb) {
  const int n = blockIdx.x, t = threadIdx.x;
  if (n >= 512) {
    if (n < 520) {               // eq_w (d,e,m) -> Wt[m][e][d]
      const int m = n - 512;
      for (int idx = t; idx < 4096; idx += 256) {
        int e = idx >> 6, d = idx & 63;
        Wt[m*4096 + idx] = eqw[d*512 + e*8 + m];
      }
    } else {                     // fc_w f32 -> bf16 (same [e][k] layout)
      int base = (n - 520)*12544 + t;
      for (int q = 0; q < 49; ++q) {
        int idx = base + q*256;
        fcwb[idx] = (short)f2bs(fcw[idx]);
      }
    }
    return;
  }
  __shared__ float si[30*30];
  __shared__ float sw[32*9];
  __shared__ float sb[32];
  __shared__ __align__(16) short inT[16*18*40];  // [yy][xx][cin stride 40]
  const int wv = t >> 6, l = t & 63, quad = l >> 4, col = l & 15;

  // conv2 B fragments from global (no LDS dependency)
  const int c_out = wv*16 + col;
  float w72[72];
  {
    const float4* src = (const float4*)(w2 + c_out*288 + quad*72);
#pragma unroll
    for (int q = 0; q < 18; ++q) {
      float4 v = src[q];
      w72[q*4+0] = v.x; w72[q*4+1] = v.y; w72[q*4+2] = v.z; w72[q*4+3] = v.w;
    }
  }
  union SU { short8 v; unsigned int u[4]; };
  short8 Bq[9];
#pragma unroll
  for (int dd = 0; dd < 9; ++dd) {
    SU b;
#pragma unroll
    for (int q = 0; q < 4; ++q)
      b.u[q] = pk2(w72[(2*q)*9 + dd], w72[(2*q+1)*9 + dd]);
    Bq[dd] = b.v;
  }
  const float bb2 = b2[c_out];

  // zero si + inT, load conv1 weights
  for (int idx = t; idx < 900; idx += 256) si[idx] = 0.f;
  {
    unsigned int* zp = (unsigned int*)inT;
    for (int idx = t; idx < 5760; idx += 256) zp[idx] = 0u;
  }
  for (int idx = t; idx < 288; idx += 256) sw[idx] = w1[idx];
  if (t < 32) sb[t] = b1[t];
  __syncthreads();
  for (int idx = t; idx < 784; idx += 256) {
    int y = idx / 28, xx = idx - y*28;
    si[(y+1)*30 + xx + 1] = x[n*784 + idx];
  }
  __syncthreads();

  // conv1 + relu + maxpool, 4 channels per thread, write bf16 into inT
  {
    const int cg = t & 7;                  // invariant across iterations (256 % 8 == 0)
    float wreg[4][9], breg[4];
#pragma unroll
    for (int cc = 0; cc < 4; ++cc) {
      breg[cc] = sb[cg*4 + cc];
#pragma unroll
      for (int q = 0; q < 9; ++q) wreg[cc][q] = sw[(cg*4 + cc)*9 + q];
    }
    for (int idx = t; idx < 1568; idx += 256) {
      int pos = idx >> 3;                  // 0..195
      int py = pos / 14, px = pos - py*14;
      float pt[4][4];
#pragma unroll
      for (int r = 0; r < 4; ++r)
#pragma unroll
        for (int q = 0; q < 4; ++q)
          pt[r][q] = si[(2*py + r)*30 + 2*px + q];
      float res[4];
#pragma unroll
      for (int cc = 0; cc < 4; ++cc) {
        float best = 0.f;
#pragma unroll
        for (int a = 0; a < 2; ++a)
#pragma unroll
          for (int b3 = 0; b3 < 2; ++b3) {
            float v = breg[cc]
              + wreg[cc][0]*pt[a+0][b3+0] + wreg[cc][1]*pt[a+0][b3+1] + wreg[cc][2]*pt[a+0][b3+2]
              + wreg[cc][3]*pt[a+1][b3+0] + wreg[cc][4]*pt[a+1][b3+1] + wreg[cc][5]*pt[a+1][b3+2]
              + wreg[cc][6]*pt[a+2][b3+0] + wreg[cc][7]*pt[a+2][b3+1] + wreg[cc][8]*pt[a+2][b3+2];
            best = fmaxf(best, v);
          }
        res[cc] = best;
      }
      uint2 pkd;
      pkd.x = pk2(res[0], res[1]);
      pkd.y = pk2(res[2], res[3]);
      *(uint2*)&inT[(py+1)*720 + (px+1)*40 + cg*4] = pkd;
    }
  }
  __syncthreads();

  // conv2 implicit-GEMM: p = pooled output row; rows y0=2p, y1=2p+1
  for (int p = 0; p < 7; ++p) {
    short8 Ar[4][3];
#pragma unroll
    for (int rr = 0; rr < 4; ++rr)
#pragma unroll
      for (int dx = 0; dx < 3; ++dx)
        Ar[rr][dx] = *(const short8*)&inT[(2*p + rr)*720 + (col + dx)*40 + quad*8];
    f32x4 a0 = {0.f,0.f,0.f,0.f}, a1 = {0.f,0.f,0.f,0.f};
#pragma unroll
    for (int dy = 0; dy < 3; ++dy)
#pragma unroll
      for (int dx = 0; dx < 3; ++dx) {
        a0 = mfma_bf16(Ar[dy][dx],     Bq[dy*3 + dx], a0);
        a1 = mfma_bf16(Ar[dy + 1][dx], Bq[dy*3 + dx], a1);
      }
#pragma unroll
    for (int a = 0; a < 2; ++a) {
      int px = quad*2 + a;
      if (px < 7) {
        float m0 = fmaxf(fmaxf(a0[2*a], a0[2*a + 1]), fmaxf(a1[2*a], a1[2*a + 1]));
        h2b[n*3136 + c_out*49 + p*7 + px] = (short)f2bs(fmaxf(m0 + bb2, 0.f));
      }
    }
  }
}

// ---------------- k3: FC 3136->64 split-K(14) bf16 MFMA -> f32 partials ----------------
__global__ __launch_bounds__(256) void k3_mfma(const short* __restrict__ h2b,
    const short* __restrict__ fcwb, float* __restrict__ part) {
  const int blk = blockIdx.x, kp = blockIdx.y, t = threadIdx.x;
  const int w = t >> 6, l = t & 63, quad = l >> 4, col = l & 15;
  const int mt = w & 1, nh = w >> 1;
  const int img = blk*32 + mt*16 + col;
  const short* Ap = h2b + img*3136 + kp*224 + quad*8;
  const short* B0 = fcwb + (nh*32 + col)*3136 + kp*224 + quad*8;
  const short* B1 = fcwb + (nh*32 + 16 + col)*3136 + kp*224 + quad*8;
  f32x4 acc0 = {0.f,0.f,0.f,0.f}, acc1 = {0.f,0.f,0.f,0.f};
#pragma unroll
  for (int q = 0; q < 7; ++q) {
    short8 A  = *(const short8*)(Ap + q*32);
    short8 b0 = *(const short8*)(B0 + q*32);
    short8 b1 = *(const short8*)(B1 + q*32);
    acc0 = mfma_bf16(A, b0, acc0);
    acc1 = mfma_bf16(A, b1, acc1);
  }
  const int e0 = nh*32 + col, e1 = e0 + 16;
  const int base = blk*32 + mt*16 + quad*4;
  float* dst = part + kp*32768;
#pragma unroll
  for (int r = 0; r < 4; ++r) {
    dst[(base + r)*64 + e0] = acc0[r];
    dst[(base + r)*64 + e1] = acc1[r];
  }
}

// ---------------- k4: reduce partials + bias + relu -> feat; s, t7c, zero x8/cnt ----------------
__global__ __launch_bounds__(256) void k4_prep(const float* __restrict__ part,
    const float* __restrict__ fb, const float* __restrict__ Wt,
    const float* __restrict__ eqb, float* __restrict__ feat,
    float* __restrict__ s, float* __restrict__ t7c, float* __restrict__ x8,
    int* __restrict__ cnt) {
  __shared__ __align__(16) float sf[2048];
  __shared__ float ss[64];
  const int b = blockIdx.x, t = threadIdx.x;
  for (int v4 = t; v4 < 512; v4 += 256) {
    float4 a = {0.f, 0.f, 0.f, 0.f};
#pragma unroll
    for (int kp = 0; kp < 14; ++kp) {
      float4 p = *(const float4*)&part[kp*32768 + b*2048 + v4*4];
      a.x += p.x; a.y += p.y; a.z += p.z; a.w += p.w;
    }
    float4 fbv = *(const float4*)&fb[(v4*4) & 63];
    float4 r;
    r.x = fmaxf(a.x + fbv.x, 0.f);
    r.y = fmaxf(a.y + fbv.y, 0.f);
    r.z = fmaxf(a.z + fbv.z, 0.f);
    r.w = fmaxf(a.w + fbv.w, 0.f);
    *(float4*)&sf[v4*4] = r;
    *(float4*)&feat[b*2048 + v4*4] = r;
  }
  __syncthreads();
  if (t < 64) {
    float a = 0.f;
    for (int i = 0; i < 32; ++i) a += sf[i*64 + t];
    a *= (1.f/32.f);
    s[b*64 + t] = a;
    ss[t] = a;
  }
  __syncthreads();
  if (t < 64) {
    const float* W7 = Wt + 7*4096 + t*64;   // [m=7][e=t][d]
    float t7 = 0.f;
    for (int d = 0; d < 64; ++d) {
      float sv = ss[d];
      t7 += sv*sv*sv * W7[d];
    }
    t7c[b*64 + t] = t7 + eqb[t];
    x8[b*64 + t] = 0.f;
  }
  if (t == 0) cnt[b] = 0;
}

// ---------------- k5: fused equivariant layer via bf16 MFMA; last block per b does k6 ----------------
__global__ __launch_bounds__(256, 2) void k5_mfma(const float* __restrict__ feat,
    const float* __restrict__ s_, const float* __restrict__ Wt,
    const float* __restrict__ t7c, float* __restrict__ x8, int* __restrict__ cnt,
    const float* __restrict__ ow, const float* __restrict__ ob,
    float* __restrict__ out) {
  __shared__ __align__(16) float Fm[32*68];
  __shared__ __align__(16) float FI[64];
  __shared__ __align__(16) float SV[64];
  __shared__ __align__(16) float C0[64];
  __shared__ float C0P[128];
  __shared__ float KCf[32*68];
  __shared__ float JCf[32*68];
  __shared__ float RED[256];
  __shared__ int isLast;
  __shared__ __align__(16) short Fb[32*72];
  __shared__ __align__(16) short QPb[64*72];
  __shared__ __align__(16) short G2b[64*72];
  __shared__ __align__(16) short G3b[64*72];

  const int i = blockIdx.x, b = blockIdx.y, t = threadIdx.x;
  const int w = t >> 6, l = t & 63, quad = l >> 4, col = l & 15;

  for (int idx = t; idx < 2048; idx += 256) {
    int r = idx >> 6, d = idx & 63;
    float v = feat[b*2048 + idx];
    Fm[r*68 + d] = v;
    Fb[r*72 + d] = (short)f2bs(v);
  }
  if (t < 64) { FI[t] = feat[b*2048 + i*64 + t]; SV[t] = s_[b*64 + t]; }
  __syncthreads();

  {
    const int e = t >> 2, dbase = (t & 3) * 16;
    const float* W0 = Wt + 0*4096 + e*64;
    const float* W1 = Wt + 1*4096 + e*64;
    const float* W2 = Wt + 2*4096 + e*64;
    const float* W3 = Wt + 3*4096 + e*64;
    const float* W4 = Wt + 4*4096 + e*64;
    const float* W5 = Wt + 5*4096 + e*64;
#pragma unroll
    for (int q = 0; q < 4; ++q) {
      int off = dbase + q*4;
      float4 fi4 = *(const float4*)&FI[off];
      float4 sv4 = *(const float4*)&SV[off];
      float4 w0 = *(const float4*)&W0[off];
      float4 w1 = *(const float4*)&W1[off];
      float4 w2 = *(const float4*)&W2[off];
      float4 w3 = *(const float4*)&W3[off];
      float4 w4 = *(const float4*)&W4[off];
      float4 w5 = *(const float4*)&W5[off];
      float4 qp = fi4*w0 + sv4*w1;
      float4 g2 = sv4*(fi4*w2 + sv4*w4);
      float4 g3 = sv4*(fi4*w3 + sv4*w5);
      stb4(&QPb[e*72 + off], qp);
      stb4(&G2b[e*72 + off], g2);
      stb4(&G3b[e*72 + off], g3);
    }
  }
  if (t < 128) {
    int e = t & 63, dh = t >> 6;
    const float* W6 = Wt + 6*4096 + e*64 + dh*32;
    const float* fip = FI + dh*32;
    const float* svp = SV + dh*32;
    float a = 0.f;
#pragma unroll
    for (int dd = 0; dd < 32; ++dd) {
      float sd = svp[dd];
      a += sd*sd*fip[dd]*W6[dd];
    }
    C0P[dh*64 + e] = a;
  }
  __syncthreads();

  if (w < 2) {
    const short* G = w ? G3b : G2b;
    float* DST = w ? JCf : KCf;
    short8 Bf[4][2];
#pragma unroll
    for (int n = 0; n < 4; ++n)
#pragma unroll
      for (int s2 = 0; s2 < 2; ++s2)
        Bf[n][s2] = *(const short8*)&G[(n*16 + col)*72 + s2*32 + quad*8];
#pragma unroll
    for (int m = 0; m < 2; ++m) {
      short8 A0 = *(const short8*)&Fb[(m*16 + col)*72 + quad*8];
      short8 A1 = *(const short8*)&Fb[(m*16 + col)*72 + 32 + quad*8];
#pragma unroll
      for (int n = 0; n < 4; ++n) {
        f32x4 z = {0.f, 0.f, 0.f, 0.f};
        f32x4 ac = mfma_bf16(A1, Bf[n][1], mfma_bf16(A0, Bf[n][0], z));
#pragma unroll
        for (int r = 0; r < 4; ++r)
          DST[(m*16 + quad*4 + r)*68 + n*16 + col] = ac[r];
      }
    }
  } else if (w == 2) {
    C0[l] = C0P[l] + C0P[64 + l] + t7c[b*64 + l];
  }
  __syncthreads();

  float c0v[4];
#pragma unroll
  for (int n = 0; n < 4; ++n) c0v[n] = C0[n*16 + col];
  float jcq[8][4];
#pragma unroll
  for (int jj = 0; jj < 8; ++jj)
#pragma unroll
    for (int n = 0; n < 4; ++n)
      jcq[jj][n] = JCf[(w*8 + jj)*68 + n*16 + col] + c0v[n];
  float kcv[2][4][4];
#pragma unroll
  for (int kb2 = 0; kb2 < 2; ++kb2)
#pragma unroll
    for (int r = 0; r < 4; ++r)
#pragma unroll
      for (int n = 0; n < 4; ++n)
        kcv[kb2][r][n] = KCf[(kb2*16 + quad*4 + r)*68 + n*16 + col];
  short8 Bq[4][2];
#pragma unroll
  for (int n = 0; n < 4; ++n)
#pragma unroll
    for (int s2 = 0; s2 < 2; ++s2)
      Bq[n][s2] = *(const short8*)&QPb[(n*16 + col)*72 + s2*32 + quad*8];

  float4 fkv[2][4];
#pragma unroll
  for (int kb2 = 0; kb2 < 2; ++kb2) {
    const float* fk = &Fm[(kb2*16 + col)*68 + quad*8];
    fkv[kb2][0] = *(const float4*)(fk);
    fkv[kb2][1] = *(const float4*)(fk + 4);
    fkv[kb2][2] = *(const float4*)(fk + 32);
    fkv[kb2][3] = *(const float4*)(fk + 36);
  }

  float sum[4] = {0.f, 0.f, 0.f, 0.f};
  union SU { short8 v; unsigned int u[4]; };

#pragma unroll
  for (int jj = 0; jj < 8; ++jj) {
    const float* fj = &Fm[(w*8 + jj)*68 + quad*8];
    float4 j0 = *(const float4*)(fj);
    float4 j1 = *(const float4*)(fj + 4);
    float4 j2 = *(const float4*)(fj + 32);
    float4 j3 = *(const float4*)(fj + 36);
#pragma unroll
    for (int kb2 = 0; kb2 < 2; ++kb2) {
      float4 k0 = fkv[kb2][0], k1 = fkv[kb2][1];
      float4 k2v = fkv[kb2][2], k3v = fkv[kb2][3];
      SU A0, A1;
      A0.u[0] = pk2(j0.x*k0.x, j0.y*k0.y);
      A0.u[1] = pk2(j0.z*k0.z, j0.w*k0.w);
      A0.u[2] = pk2(j1.x*k1.x, j1.y*k1.y);
      A0.u[3] = pk2(j1.z*k1.z, j1.w*k1.w);
      A1.u[0] = pk2(j2.x*k2v.x, j2.y*k2v.y);
      A1.u[1] = pk2(j2.z*k2v.z, j2.w*k2v.w);
      A1.u[2] = pk2(j3.x*k3v.x, j3.y*k3v.y);
      A1.u[3] = pk2(j3.z*k3v.z, j3.w*k3v.w);
      f32x4 ac[4];
#pragma unroll
      for (int n = 0; n < 4; ++n) {
        f32x4 z = {0.f, 0.f, 0.f, 0.f};
        ac[n] = mfma_bf16(A1.v, Bq[n][1], mfma_bf16(A0.v, Bq[n][0], z));
      }
#pragma unroll
      for (int n = 0; n < 4; ++n)
#pragma unroll
        for (int r = 0; r < 4; ++r) {
          float v = ac[n][r] + kcv[kb2][r][n] + jcq[jj][n];
          sum[n] += fmaxf(v, 0.f);
        }
    }
  }

#pragma unroll
  for (int n = 0; n < 4; ++n) {
    float v = sum[n];
    v += __shfl_xor(v, 16, 64);
    v += __shfl_xor(v, 32, 64);
    if (l < 16) RED[w*64 + n*16 + l] = v;
  }
  __syncthreads();
  if (t < 64) {
    float tot = RED[t] + RED[64 + t] + RED[128 + t] + RED[192 + t];
    atomicAdd(&x8[b*64 + t], tot);
  }
  __syncthreads();           // drains the atomics (vmcnt) before ticket
  if (t == 0) {
    __threadfence();
    int old = atomicAdd(&cnt[b], 1);
    isLast = (old == 31);
  }
  __syncthreads();
  if (isLast) {
    __threadfence();
    if (t < 64) {
      float xv = atomicAdd(&x8[b*64 + t], 0.0f);   // coherent read
      float v = fmaxf(xv * (1.f/32768.f), 0.f) * ow[t];
#pragma unroll
      for (int off = 32; off > 0; off >>= 1) v += __shfl_down(v, off, 64);
      if (t == 0) out[b] = v + ob[0];
    }
  }
}

extern "C" void kernel_launch(void* const* d_in, const int* in_sizes, int n_in,
                              void* d_out, int out_size, void* d_ws, size_t ws_size,
                              hipStream_t stream) {
  const float* x   = (const float*)d_in[0];
  const float* c1w = (const float*)d_in[1];
  const float* c1b = (const float*)d_in[2];
  const float* c2w = (const float*)d_in[3];
  const float* c2b = (const float*)d_in[4];
  const float* fcw = (const float*)d_in[5];
  const float* fcb = (const float*)d_in[6];
  const float* eqw = (const float*)d_in[7];
  const float* eqb = (const float*)d_in[8];
  const float* ow  = (const float*)d_in[9];
  const float* ob  = (const float*)d_in[10];
  float* out = (float*)d_out;

  short* h2b  = (short*)d_ws;             // 512*3136 bf16
  float* feat = (float*)(h2b + 512*3136); // 512*64 f32
  float* s    = feat + 512*64;            // 16*64
  float* t7c  = s + 1024;
  float* x8   = t7c + 1024;
  int*   cnt  = (int*)(x8 + 1024);        // 16 (pad to 16 floats)
  float* Wt   = (float*)(cnt + 16);       // 8*64*64
  short* fcwb = (short*)(Wt + 32768);     // 64*3136 bf16
  float* part = (float*)(fcwb + 200704);  // 14*512*64 f32

  hipLaunchKernelGGL(k12_conv, dim3(536), dim3(256), 0, stream,
                     x, c1w, c1b, c2w, c2b, h2b, eqw, Wt, fcw, fcwb);
  hipLaunchKernelGGL(k3_mfma,  dim3(16, 14), dim3(256), 0, stream, h2b, fcwb, part);
  hipLaunchKernelGGL(k4_prep,  dim3(16),  dim3(256), 0, stream,
                     part, fcb, Wt, eqb, feat, s, t7c, x8, cnt);
  hipLaunchKernelGGL(k5_mfma,  dim3(32, 16), dim3(256), 0, stream,
                     feat, s, Wt, t7c, x8, cnt, ow, ob, out);
}

// Round 8
// 122.305 us; speedup vs baseline: 1.1575x; 1.1575x over previous
//
#include <hip/hip_runtime.h>
#include <hip/hip_bf16.h>

// B=16, K=32, H=W=28, HID=OUT=64, NOPS=8
// ws layout: h2b bf16[512*3136] | feat f32[512*64] | s[1024] | t7c[1024]
//            | x8p f32[512*64] | W7t f32[4096] | Wtb bf16[7*4096] ([m][e][d])
//            | fcwb bf16[64*3136] | part f32[14*512*64]

typedef __attribute__((ext_vector_type(8))) short short8;
typedef __attribute__((ext_vector_type(4))) float f32x4;

__device__ __forceinline__ f32x4 mfma_bf16(short8 a, short8 b, f32x4 c) {
  return __builtin_amdgcn_mfma_f32_16x16x32_bf16(a, b, c, 0, 0, 0);
}

// float -> bf16 bits, round-to-nearest-even (finite inputs only)
__device__ __forceinline__ unsigned short f2bs(float f) {
  unsigned int u = __float_as_uint(f);
  unsigned int r = u + 0x7fffu + ((u >> 16) & 1u);
  return (unsigned short)(r >> 16);
}
// packed 2xfp32 -> 2xbf16 (v_cvt_pk_bf16_f32 on gfx950)
__device__ __forceinline__ unsigned int pk2(float x, float y) {
  union { __hip_bfloat162 h; unsigned int u; } cv;
  cv.h = __float22bfloat162_rn(make_float2(x, y));
  return cv.u;
}
// unpack 8 bf16 (16B) -> 8 f32
__device__ __forceinline__ void ub8(const short* p, float* f) {
  uint4 u = *(const uint4*)p;
  f[0] = __uint_as_float(u.x << 16); f[1] = __uint_as_float(u.x & 0xffff0000u);
  f[2] = __uint_as_float(u.y << 16); f[3] = __uint_as_float(u.y & 0xffff0000u);
  f[4] = __uint_as_float(u.z << 16); f[5] = __uint_as_float(u.z & 0xffff0000u);
  f[6] = __uint_as_float(u.w << 16); f[7] = __uint_as_float(u.w & 0xffff0000u);
}

// ---------------- k12: fused conv1+pool -> LDS -> conv2(MFMA)+pool -> h2b ----------------
// blocks >= 512 do weight prep (W7t f32, Wtb bf16, fcwb cast)
__global__ __launch_bounds__(256, 2) void k12_conv(const float* __restrict__ x,
    const float* __restrict__ w1, const float* __restrict__ b1,
    const float* __restrict__ w2, const float* __restrict__ b2,
    short* __restrict__ h2b,
    const float* __restrict__ eqw, float* __restrict__ W7t, short* __restrict__ Wtb,
    const float* __restrict__ fcw, short* __restrict__ fcwb) {
  const int n = blockIdx.x, t = threadIdx.x;
  if (n >= 512) {
    if (n < 520) {               // eq_w (d,e,m) -> W7t f32 / Wtb bf16, [e][d]
      const int m = n - 512;
      for (int idx = t; idx < 4096; idx += 256) {
        int e = idx >> 6, d = idx & 63;
        float v = eqw[d*512 + e*8 + m];
        if (m == 7) W7t[idx] = v;
        else        Wtb[m*4096 + idx] = (short)f2bs(v);
      }
    } else {                     // fc_w f32 -> bf16 (same [e][k] layout)
      int base = (n - 520)*12544 + t;
      for (int q = 0; q < 49; ++q) {
        int idx = base + q*256;
        fcwb[idx] = (short)f2bs(fcw[idx]);
      }
    }
    return;
  }
  __shared__ float si[30*30];
  __shared__ float sw[32*9];
  __shared__ float sb[32];
  __shared__ __align__(16) short inT[16*18*40];  // [yy][xx][cin stride 40]
  const int wv = t >> 6, l = t & 63, quad = l >> 4, col = l & 15;

  // conv2 B fragments from global (no LDS dependency)
  const int c_out = wv*16 + col;
  float w72[72];
  {
    const float4* src = (const float4*)(w2 + c_out*288 + quad*72);
#pragma unroll
    for (int q = 0; q < 18; ++q) {
      float4 v = src[q];
      w72[q*4+0] = v.x; w72[q*4+1] = v.y; w72[q*4+2] = v.z; w72[q*4+3] = v.w;
    }
  }
  union SU { short8 v; unsigned int u[4]; };
  short8 Bq[9];
#pragma unroll
  for (int dd = 0; dd < 9; ++dd) {
    SU b;
#pragma unroll
    for (int q = 0; q < 4; ++q)
      b.u[q] = pk2(w72[(2*q)*9 + dd], w72[(2*q+1)*9 + dd]);
    Bq[dd] = b.v;
  }
  const float bb2 = b2[c_out];

  for (int idx = t; idx < 900; idx += 256) si[idx] = 0.f;
  {
    unsigned int* zp = (unsigned int*)inT;
    for (int idx = t; idx < 5760; idx += 256) zp[idx] = 0u;
  }
  for (int idx = t; idx < 288; idx += 256) sw[idx] = w1[idx];
  if (t < 32) sb[t] = b1[t];
  __syncthreads();
  for (int idx = t; idx < 784; idx += 256) {
    int y = idx / 28, xx = idx - y*28;
    si[(y+1)*30 + xx + 1] = x[n*784 + idx];
  }
  __syncthreads();

  // conv1 + relu + maxpool, 4 channels per thread, write bf16 into inT
  {
    const int cg = t & 7;
    float wreg[4][9], breg[4];
#pragma unroll
    for (int cc = 0; cc < 4; ++cc) {
      breg[cc] = sb[cg*4 + cc];
#pragma unroll
      for (int q = 0; q < 9; ++q) wreg[cc][q] = sw[(cg*4 + cc)*9 + q];
    }
    for (int idx = t; idx < 1568; idx += 256) {
      int pos = idx >> 3;
      int py = pos / 14, px = pos - py*14;
      float pt[4][4];
#pragma unroll
      for (int r = 0; r < 4; ++r)
#pragma unroll
        for (int q = 0; q < 4; ++q)
          pt[r][q] = si[(2*py + r)*30 + 2*px + q];
      float res[4];
#pragma unroll
      for (int cc = 0; cc < 4; ++cc) {
        float best = 0.f;
#pragma unroll
        for (int a = 0; a < 2; ++a)
#pragma unroll
          for (int b3 = 0; b3 < 2; ++b3) {
            float v = breg[cc]
              + wreg[cc][0]*pt[a+0][b3+0] + wreg[cc][1]*pt[a+0][b3+1] + wreg[cc][2]*pt[a+0][b3+2]
              + wreg[cc][3]*pt[a+1][b3+0] + wreg[cc][4]*pt[a+1][b3+1] + wreg[cc][5]*pt[a+1][b3+2]
              + wreg[cc][6]*pt[a+2][b3+0] + wreg[cc][7]*pt[a+2][b3+1] + wreg[cc][8]*pt[a+2][b3+2];
            best = fmaxf(best, v);
          }
        res[cc] = best;
      }
      uint2 pkd;
      pkd.x = pk2(res[0], res[1]);
      pkd.y = pk2(res[2], res[3]);
      *(uint2*)&inT[(py+1)*720 + (px+1)*40 + cg*4] = pkd;
    }
  }
  __syncthreads();

  for (int p = 0; p < 7; ++p) {
    short8 Ar[4][3];
#pragma unroll
    for (int rr = 0; rr < 4; ++rr)
#pragma unroll
      for (int dx = 0; dx < 3; ++dx)
        Ar[rr][dx] = *(const short8*)&inT[(2*p + rr)*720 + (col + dx)*40 + quad*8];
    f32x4 a0 = {0.f,0.f,0.f,0.f}, a1 = {0.f,0.f,0.f,0.f};
#pragma unroll
    for (int dy = 0; dy < 3; ++dy)
#pragma unroll
      for (int dx = 0; dx < 3; ++dx) {
        a0 = mfma_bf16(Ar[dy][dx],     Bq[dy*3 + dx], a0);
        a1 = mfma_bf16(Ar[dy + 1][dx], Bq[dy*3 + dx], a1);
      }
#pragma unroll
    for (int a = 0; a < 2; ++a) {
      int px = quad*2 + a;
      if (px < 7) {
        float m0 = fmaxf(fmaxf(a0[2*a], a0[2*a + 1]), fmaxf(a1[2*a], a1[2*a + 1]));
        h2b[n*3136 + c_out*49 + p*7 + px] = (short)f2bs(fmaxf(m0 + bb2, 0.f));
      }
    }
  }
}

// ---------------- k3: FC 3136->64 split-K(14) bf16 MFMA -> f32 partials ----------------
__global__ __launch_bounds__(256) void k3_mfma(const short* __restrict__ h2b,
    const short* __restrict__ fcwb, float* __restrict__ part) {
  const int blk = blockIdx.x, kp = blockIdx.y, t = threadIdx.x;
  const int w = t >> 6, l = t & 63, quad = l >> 4, col = l & 15;
  const int mt = w & 1, nh = w >> 1;
  const int img = blk*32 + mt*16 + col;
  const short* Ap = h2b + img*3136 + kp*224 + quad*8;
  const short* B0 = fcwb + (nh*32 + col)*3136 + kp*224 + quad*8;
  const short* B1 = fcwb + (nh*32 + 16 + col)*3136 + kp*224 + quad*8;
  f32x4 acc0 = {0.f,0.f,0.f,0.f}, acc1 = {0.f,0.f,0.f,0.f};
#pragma unroll
  for (int q = 0; q < 7; ++q) {
    short8 A  = *(const short8*)(Ap + q*32);
    short8 b0 = *(const short8*)(B0 + q*32);
    short8 b1 = *(const short8*)(B1 + q*32);
    acc0 = mfma_bf16(A, b0, acc0);
    acc1 = mfma_bf16(A, b1, acc1);
  }
  const int e0 = nh*32 + col, e1 = e0 + 16;
  const int base = blk*32 + mt*16 + quad*4;
  float* dst = part + kp*32768;
#pragma unroll
  for (int r = 0; r < 4; ++r) {
    dst[(base + r)*64 + e0] = acc0[r];
    dst[(base + r)*64 + e1] = acc1[r];
  }
}

// ---------------- k4: reduce partials + bias + relu -> feat; s, t7c ----------------
__global__ __launch_bounds__(256) void k4_prep(const float* __restrict__ part,
    const float* __restrict__ fb, const float* __restrict__ W7t,
    const float* __restrict__ eqb, float* __restrict__ feat,
    float* __restrict__ s, float* __restrict__ t7c) {
  __shared__ __align__(16) float sf[2048];
  __shared__ float ss[64];
  const int b = blockIdx.x, t = threadIdx.x;
  for (int v4 = t; v4 < 512; v4 += 256) {
    float4 a = {0.f, 0.f, 0.f, 0.f};
#pragma unroll
    for (int kp = 0; kp < 14; ++kp) {
      float4 p = *(const float4*)&part[kp*32768 + b*2048 + v4*4];
      a.x += p.x; a.y += p.y; a.z += p.z; a.w += p.w;
    }
    float4 fbv = *(const float4*)&fb[(v4*4) & 63];
    float4 r;
    r.x = fmaxf(a.x + fbv.x, 0.f);
    r.y = fmaxf(a.y + fbv.y, 0.f);
    r.z = fmaxf(a.z + fbv.z, 0.f);
    r.w = fmaxf(a.w + fbv.w, 0.f);
    *(float4*)&sf[v4*4] = r;
    *(float4*)&feat[b*2048 + v4*4] = r;
  }
  __syncthreads();
  if (t < 64) {
    float a = 0.f;
    for (int i = 0; i < 32; ++i) a += sf[i*64 + t];
    a *= (1.f/32.f);
    s[b*64 + t] = a;
    ss[t] = a;
  }
  __syncthreads();
  if (t < 64) {
    const float* W7 = W7t + t*64;   // [e=t][d]
    float t7 = 0.f;
    for (int d = 0; d < 64; ++d) {
      float sv = ss[d];
      t7 += sv*sv*sv * W7[d];
    }
    t7c[b*64 + t] = t7 + eqb[t];
  }
}

// ---------------- k5: fused equivariant layer via bf16 MFMA -> x8p partials ----------------
__global__ __launch_bounds__(256, 2) void k5_mfma(const float* __restrict__ feat,
    const float* __restrict__ s_, const short* __restrict__ Wtb,
    const float* __restrict__ t7c, float* __restrict__ x8p) {
  __shared__ __align__(16) float Fm[32*68];
  __shared__ __align__(16) float FI[64];
  __shared__ __align__(16) float SV[64];
  __shared__ __align__(16) float C0[64];
  __shared__ float C0P[128];
  __shared__ float KCf[32*68];
  __shared__ float JCf[32*68];
  __shared__ float RED[256];
  __shared__ __align__(16) short Fb[32*72];
  __shared__ __align__(16) short QPb[64*72];
  __shared__ __align__(16) short G2b[64*72];
  __shared__ __align__(16) short G3b[64*72];

  const int i = blockIdx.x, b = blockIdx.y, t = threadIdx.x;
  const int w = t >> 6, l = t & 63, quad = l >> 4, col = l & 15;

  for (int idx = t; idx < 2048; idx += 256) {
    int r = idx >> 6, d = idx & 63;
    float v = feat[b*2048 + idx];
    Fm[r*68 + d] = v;
    Fb[r*72 + d] = (short)f2bs(v);
  }
  if (t < 64) { FI[t] = feat[b*2048 + i*64 + t]; SV[t] = s_[b*64 + t]; }
  __syncthreads();

  // P0b: QPb = fi*W0 + s*W1 ; G2b = s*(fi*W2 + s*W4) ; G3b = s*(fi*W3 + s*W5)  (bf16 weights)
  {
    const int e = t >> 2, dbase = (t & 3) * 16;
#pragma unroll
    for (int h = 0; h < 2; ++h) {
      int off = dbase + h*8;
      float w0[8], w1[8], w2[8], w3[8], w4[8], w5[8];
      ub8(&Wtb[0*4096 + e*64 + off], w0);
      ub8(&Wtb[1*4096 + e*64 + off], w1);
      ub8(&Wtb[2*4096 + e*64 + off], w2);
      ub8(&Wtb[3*4096 + e*64 + off], w3);
      ub8(&Wtb[4*4096 + e*64 + off], w4);
      ub8(&Wtb[5*4096 + e*64 + off], w5);
      uint4 qv, g2v, g3v;
      unsigned int* qp = &qv.x;
      unsigned int* g2p = &g2v.x;
      unsigned int* g3p = &g3v.x;
#pragma unroll
      for (int j = 0; j < 4; ++j) {
        float fi0 = FI[off + 2*j],     fi1 = FI[off + 2*j + 1];
        float s0  = SV[off + 2*j],     s1  = SV[off + 2*j + 1];
        float q0 = fi0*w0[2*j]   + s0*w1[2*j];
        float q1 = fi1*w0[2*j+1] + s1*w1[2*j+1];
        float a0 = s0*(fi0*w2[2*j]   + s0*w4[2*j]);
        float a1 = s1*(fi1*w2[2*j+1] + s1*w4[2*j+1]);
        float c0 = s0*(fi0*w3[2*j]   + s0*w5[2*j]);
        float c1 = s1*(fi1*w3[2*j+1] + s1*w5[2*j+1]);
        qp[j]  = pk2(q0, q1);
        g2p[j] = pk2(a0, a1);
        g3p[j] = pk2(c0, c1);
      }
      *(uint4*)&QPb[e*72 + off] = qv;
      *(uint4*)&G2b[e*72 + off] = g2v;
      *(uint4*)&G3b[e*72 + off] = g3v;
    }
  }
  if (t < 128) {
    int e = t & 63, dh = t >> 6;
    const short* W6 = Wtb + 6*4096 + e*64 + dh*32;
    float a = 0.f;
#pragma unroll
    for (int g = 0; g < 4; ++g) {
      float wf[8];
      ub8(&W6[g*8], wf);
#pragma unroll
      for (int dd = 0; dd < 8; ++dd) {
        int d = dh*32 + g*8 + dd;
        float sd = SV[d];
        a += sd*sd*FI[d]*wf[dd];
      }
    }
    C0P[dh*64 + e] = a;
  }
  __syncthreads();

  if (w < 2) {
    const short* G = w ? G3b : G2b;
    float* DST = w ? JCf : KCf;
    short8 Bf[4][2];
#pragma unroll
    for (int n = 0; n < 4; ++n)
#pragma unroll
      for (int s2 = 0; s2 < 2; ++s2)
        Bf[n][s2] = *(const short8*)&G[(n*16 + col)*72 + s2*32 + quad*8];
#pragma unroll
    for (int m = 0; m < 2; ++m) {
      short8 A0 = *(const short8*)&Fb[(m*16 + col)*72 + quad*8];
      short8 A1 = *(const short8*)&Fb[(m*16 + col)*72 + 32 + quad*8];
#pragma unroll
      for (int n = 0; n < 4; ++n) {
        f32x4 z = {0.f, 0.f, 0.f, 0.f};
        f32x4 ac = mfma_bf16(A1, Bf[n][1], mfma_bf16(A0, Bf[n][0], z));
#pragma unroll
        for (int r = 0; r < 4; ++r)
          DST[(m*16 + quad*4 + r)*68 + n*16 + col] = ac[r];
      }
    }
  } else if (w == 2) {
    C0[l] = C0P[l] + C0P[64 + l] + t7c[b*64 + l];
  }
  __syncthreads();

  float c0v[4];
#pragma unroll
  for (int n = 0; n < 4; ++n) c0v[n] = C0[n*16 + col];
  float jcq[8][4];
#pragma unroll
  for (int jj = 0; jj < 8; ++jj)
#pragma unroll
    for (int n = 0; n < 4; ++n)
      jcq[jj][n] = JCf[(w*8 + jj)*68 + n*16 + col] + c0v[n];
  float kcv[2][4][4];
#pragma unroll
  for (int kb2 = 0; kb2 < 2; ++kb2)
#pragma unroll
    for (int r = 0; r < 4; ++r)
#pragma unroll
      for (int n = 0; n < 4; ++n)
        kcv[kb2][r][n] = KCf[(kb2*16 + quad*4 + r)*68 + n*16 + col];
  short8 Bq[4][2];
#pragma unroll
  for (int n = 0; n < 4; ++n)
#pragma unroll
    for (int s2 = 0; s2 < 2; ++s2)
      Bq[n][s2] = *(const short8*)&QPb[(n*16 + col)*72 + s2*32 + quad*8];

  float4 fkv[2][4];
#pragma unroll
  for (int kb2 = 0; kb2 < 2; ++kb2) {
    const float* fk = &Fm[(kb2*16 + col)*68 + quad*8];
    fkv[kb2][0] = *(const float4*)(fk);
    fkv[kb2][1] = *(const float4*)(fk + 4);
    fkv[kb2][2] = *(const float4*)(fk + 32);
    fkv[kb2][3] = *(const float4*)(fk + 36);
  }

  float sum[4] = {0.f, 0.f, 0.f, 0.f};
  union SU { short8 v; unsigned int u[4]; };

#pragma unroll
  for (int jj = 0; jj < 8; ++jj) {
    const float* fj = &Fm[(w*8 + jj)*68 + quad*8];
    float4 j0 = *(const float4*)(fj);
    float4 j1 = *(const float4*)(fj + 4);
    float4 j2 = *(const float4*)(fj + 32);
    float4 j3 = *(const float4*)(fj + 36);
#pragma unroll
    for (int kb2 = 0; kb2 < 2; ++kb2) {
      float4 k0 = fkv[kb2][0], k1 = fkv[kb2][1];
      float4 k2v = fkv[kb2][2], k3v = fkv[kb2][3];
      SU A0, A1;
      A0.u[0] = pk2(j0.x*k0.x, j0.y*k0.y);
      A0.u[1] = pk2(j0.z*k0.z, j0.w*k0.w);
      A0.u[2] = pk2(j1.x*k1.x, j1.y*k1.y);
      A0.u[3] = pk2(j1.z*k1.z, j1.w*k1.w);
      A1.u[0] = pk2(j2.x*k2v.x, j2.y*k2v.y);
      A1.u[1] = pk2(j2.z*k2v.z, j2.w*k2v.w);
      A1.u[2] = pk2(j3.x*k3v.x, j3.y*k3v.y);
      A1.u[3] = pk2(j3.z*k3v.z, j3.w*k3v.w);
      f32x4 ac[4];
#pragma unroll
      for (int n = 0; n < 4; ++n) {
        f32x4 z = {0.f, 0.f, 0.f, 0.f};
        ac[n] = mfma_bf16(A1.v, Bq[n][1], mfma_bf16(A0.v, Bq[n][0], z));
      }
#pragma unroll
      for (int n = 0; n < 4; ++n)
#pragma unroll
        for (int r = 0; r < 4; ++r) {
          float v = ac[n][r] + kcv[kb2][r][n] + jcq[jj][n];
          sum[n] += fmaxf(v, 0.f);
        }
    }
  }

#pragma unroll
  for (int n = 0; n < 4; ++n) {
    float v = sum[n];
    v += __shfl_xor(v, 16, 64);
    v += __shfl_xor(v, 32, 64);
    if (l < 16) RED[w*64 + n*16 + l] = v;
  }
  __syncthreads();
  if (t < 64) {
    float tot = RED[t] + RED[64 + t] + RED[128 + t] + RED[192 + t];
    x8p[(b*32 + i)*64 + t] = tot;            // non-atomic partial
  }
}

// ---------------- k6: reduce x8p over i; x9 = relu(x8/K^3); out = x9 @ out_w.T + out_b ----------------
__global__ __launch_bounds__(64) void k6_out(const float* __restrict__ x8p,
    const float* __restrict__ ow, const float* __restrict__ ob,
    float* __restrict__ out) {
  const int bb = blockIdx.x, t = threadIdx.x;
  float a = 0.f;
#pragma unroll
  for (int i = 0; i < 32; ++i) a += x8p[(bb*32 + i)*64 + t];
  float v = fmaxf(a * (1.f/32768.f), 0.f) * ow[t];
#pragma unroll
  for (int off = 32; off > 0; off >>= 1) v += __shfl_down(v, off, 64);
  if (t == 0) out[bb] = v + ob[0];
}

extern "C" void kernel_launch(void* const* d_in, const int* in_sizes, int n_in,
                              void* d_out, int out_size, void* d_ws, size_t ws_size,
                              hipStream_t stream) {
  const float* x   = (const float*)d_in[0];
  const float* c1w = (const float*)d_in[1];
  const float* c1b = (const float*)d_in[2];
  const float* c2w = (const float*)d_in[3];
  const float* c2b = (const float*)d_in[4];
  const float* fcw = (const float*)d_in[5];
  const float* fcb = (const float*)d_in[6];
  const float* eqw = (const float*)d_in[7];
  const float* eqb = (const float*)d_in[8];
  const float* ow  = (const float*)d_in[9];
  const float* ob  = (const float*)d_in[10];
  float* out = (float*)d_out;

  short* h2b  = (short*)d_ws;             // 512*3136 bf16
  float* feat = (float*)(h2b + 512*3136); // 512*64 f32
  float* s    = feat + 32768;             // 1024
  float* t7c  = s + 1024;                 // 1024
  float* x8p  = t7c + 1024;               // 512*64
  float* W7t  = x8p + 32768;              // 4096
  short* Wtb  = (short*)(W7t + 4096);     // 7*4096 bf16
  short* fcwb = Wtb + 7*4096;             // 64*3136 bf16
  float* part = (float*)(fcwb + 200704);  // 14*512*64 f32

  hipLaunchKernelGGL(k12_conv, dim3(536), dim3(256), 0, stream,
                     x, c1w, c1b, c2w, c2b, h2b, eqw, W7t, Wtb, fcw, fcwb);
  hipLaunchKernelGGL(k3_mfma,  dim3(16, 14), dim3(256), 0, stream, h2b, fcwb, part);
  hipLaunchKernelGGL(k4_prep,  dim3(16),  dim3(256), 0, stream,
                     part, fcb, W7t, eqb, feat, s, t7c);
  hipLaunchKernelGGL(k5_mfma,  dim3(32, 16), dim3(256), 0, stream, feat, s, Wtb, t7c, x8p);
  hipLaunchKernelGGL(k6_out,   dim3(16),  dim3(64),  0, stream, x8p, ow, ob, out);
}